// Round 2
// baseline (114.842 us; speedup 1.0000x reference)
//
#include <hip/hip_runtime.h>

#define M_GT 256

// Pack per-GT data as 8 floats {x1,y1,x2,y2,area,0,0,0} so the main loop can
// fetch one GT via a single s_load_dwordx8 (uniform index -> scalar load).
__global__ __launch_bounds__(256) void prep_kernel(
    const float* __restrict__ gt_boxes, float* __restrict__ prep)
{
    int j = blockIdx.x * blockDim.x + threadIdx.x;
    if (j >= M_GT) return;
    float x1 = gt_boxes[j * 4 + 0], y1 = gt_boxes[j * 4 + 1];
    float x2 = gt_boxes[j * 4 + 2], y2 = gt_boxes[j * 4 + 3];
    float area = (x2 - x1) * (y2 - y1);
    float* o = prep + j * 8;
    o[0] = x1; o[1] = y1; o[2] = x2; o[3] = y2;
    o[4] = area; o[5] = 0.f; o[6] = 0.f; o[7] = 0.f;
}

__device__ __forceinline__ void epilogue(
    int i, float4 p, float bi, float bu, int bx,
    const float* __restrict__ gt_boxes, const int* __restrict__ gt_labels,
    float* __restrict__ out_labels, float* __restrict__ out_deltas)
{
    float max_iou = bi / bu;                 // single IEEE f32 division
    bool pos = (max_iou >= 0.5f);

    int lbl = gt_labels[bx];
    out_labels[i] = pos ? (float)lbl : 0.0f;

    float4 g = reinterpret_cast<const float4*>(gt_boxes)[bx];

    float pw = p.z - p.x;
    float ph = p.w - p.y;
    float px = p.x + 0.5f * pw;
    float py = p.y + 0.5f * ph;
    float gw = g.z - g.x;
    float gh = g.w - g.y;
    float gx = g.x + 0.5f * gw;
    float gy = g.y + 0.5f * gh;

    float tx = (gx - px) / pw;
    float ty = (gy - py) / ph;
    float tw = logf(gw / pw);
    float th = logf(gh / ph);

    float4 d;
    if (pos) { d.x = tx; d.y = ty; d.z = tw; d.w = th; }
    else     { d.x = 0.f; d.y = 0.f; d.z = 0.f; d.w = 0.f; }
    reinterpret_cast<float4*>(out_deltas)[i] = d;
}

__global__ __launch_bounds__(256) void roi_assign_kernel(
    const float* __restrict__ proposals,  // [N,4]
    const float* __restrict__ prep,       // [M_GT*8] packed GT data
    const float* __restrict__ gt_boxes,   // [M,4]
    const int*   __restrict__ gt_labels,  // [M]
    float* __restrict__ out_labels,       // [N]
    float* __restrict__ out_deltas,       // [N,4]
    int half)                             // N/2; thread t owns t and t+half
{
    int t = blockIdx.x * blockDim.x + threadIdx.x;
    if (t >= half) return;
    int iA = t;
    int iB = t + half;

    float4 pA = reinterpret_cast<const float4*>(proposals)[iA];
    float4 pB = reinterpret_cast<const float4*>(proposals)[iB];
    float areaA = (pA.z - pA.x) * (pA.w - pA.y);
    float areaB = (pB.z - pB.x) * (pB.w - pB.y);

    // best-so-far tracked as (inter, union); compare via cross-mult.
    float biA = -1.0f, buA = 1.0f; int bxA = 0;
    float biB = -1.0f, buB = 1.0f; int bxB = 0;

#pragma unroll 4
    for (int j = 0; j < M_GT; ++j) {
        // uniform index -> compiler emits s_load_dwordx8 into SGPRs
        const float4* gp = reinterpret_cast<const float4*>(prep + j * 8);
        float4 g  = gp[0];
        float4 g2 = gp[1];
        float sA  = g2.x;   // gt area

        {
            float lx = fmaxf(pA.x, g.x), ly = fmaxf(pA.y, g.y);
            float rx = fminf(pA.z, g.z), ry = fminf(pA.w, g.w);
            float w = fmaxf(rx - lx, 0.0f);
            float h = fmaxf(ry - ly, 0.0f);
            float inter = w * h;
            float uni = (areaA + sA) - inter;          // same rounding as ref
            bool upd = (inter * buA) > (biA * uni);
            biA = upd ? inter : biA;
            buA = upd ? uni   : buA;
            bxA = upd ? j     : bxA;
        }
        {
            float lx = fmaxf(pB.x, g.x), ly = fmaxf(pB.y, g.y);
            float rx = fminf(pB.z, g.z), ry = fminf(pB.w, g.w);
            float w = fmaxf(rx - lx, 0.0f);
            float h = fmaxf(ry - ly, 0.0f);
            float inter = w * h;
            float uni = (areaB + sA) - inter;
            bool upd = (inter * buB) > (biB * uni);
            biB = upd ? inter : biB;
            buB = upd ? uni   : buB;
            bxB = upd ? j     : bxB;
        }
    }

    epilogue(iA, pA, biA, buA, bxA, gt_boxes, gt_labels, out_labels, out_deltas);
    epilogue(iB, pB, biB, buB, bxB, gt_boxes, gt_labels, out_labels, out_deltas);
}

extern "C" void kernel_launch(void* const* d_in, const int* in_sizes, int n_in,
                              void* d_out, int out_size, void* d_ws, size_t ws_size,
                              hipStream_t stream) {
    const float* proposals = (const float*)d_in[0];
    const float* gt_boxes  = (const float*)d_in[1];
    const int*   gt_labels = (const int*)d_in[2];

    int N = in_sizes[0] / 4;   // 262144
    int half = N >> 1;

    float* out_labels = (float*)d_out;       // first N floats
    float* out_deltas = (float*)d_out + N;   // then N*4 floats
    float* prep = (float*)d_ws;              // M_GT*8 floats

    prep_kernel<<<1, 256, 0, stream>>>(gt_boxes, prep);

    dim3 block(256);
    dim3 grid((half + 255) / 256);
    roi_assign_kernel<<<grid, block, 0, stream>>>(
        proposals, prep, gt_boxes, gt_labels, out_labels, out_deltas, half);
}

// Round 3
// 97.781 us; speedup vs baseline: 1.1745x; 1.1745x over previous
//
#include <hip/hip_runtime.h>

#define M_GT 256

__global__ __launch_bounds__(256, 4) void roi_assign_kernel(
    const float4* __restrict__ proposals,  // [N]
    const float4* __restrict__ gt_boxes,   // [M]
    const int*    __restrict__ gt_labels,  // [M]
    float*        __restrict__ out_labels, // [N]
    float4*       __restrict__ out_deltas, // [N]
    int N)
{
    __shared__ float4 s_box[M_GT];
    __shared__ float  s_area[M_GT];

    int tid = threadIdx.x;
    // stage GT boxes + areas (block = 256 threads = M_GT)
    float4 g0 = gt_boxes[tid];
    s_box[tid]  = g0;
    s_area[tid] = (g0.z - g0.x) * (g0.w - g0.y);
    __syncthreads();

    int i = blockIdx.x * blockDim.x + tid;
    if (i >= N) return;

    float4 p = proposals[i];
    float areaA = (p.z - p.x) * (p.w - p.y);

    // two independent best-chains (even/odd j) -> 2x ILP on the select chain
    float biE = -1.f, buE = 1.f; int bxE = 0;
    float biO = -1.f, buO = 1.f; int bxO = 1;

    const float2* s_area2 = reinterpret_cast<const float2*>(s_area);

#pragma unroll 4
    for (int j = 0; j < M_GT; j += 2) {
        float4 gE = s_box[j];
        float4 gO = s_box[j + 1];
        float2 ar = s_area2[j >> 1];   // one ds_read_b64 for both areas

        {   // even chain
            float lx = fmaxf(p.x, gE.x), ly = fmaxf(p.y, gE.y);
            float rx = fminf(p.z, gE.z), ry = fminf(p.w, gE.w);
            float w = fmaxf(rx - lx, 0.f), h = fmaxf(ry - ly, 0.f);
            float inter = w * h;
            float uni = (areaA + ar.x) - inter;           // same rounding as ref
            bool upd = (inter * buE) > (biE * uni);       // exact rational compare
            biE = upd ? inter : biE;
            buE = upd ? uni   : buE;
            bxE = upd ? j     : bxE;
        }
        {   // odd chain
            float lx = fmaxf(p.x, gO.x), ly = fmaxf(p.y, gO.y);
            float rx = fminf(p.z, gO.z), ry = fminf(p.w, gO.w);
            float w = fmaxf(rx - lx, 0.f), h = fmaxf(ry - ly, 0.f);
            float inter = w * h;
            float uni = (areaA + ar.y) - inter;
            bool upd = (inter * buO) > (biO * uni);
            biO = upd ? inter : biO;
            buO = upd ? uni   : buO;
            bxO = upd ? j + 1 : bxO;
        }
    }

    // merge chains; tie (equal cross-products) -> smaller index, matching
    // jnp.argmax first-occurrence semantics
    float ca = biO * buE, cb = biE * buO;
    bool takeO = (ca > cb) || ((ca == cb) && (bxO < bxE));
    float bi = takeO ? biO : biE;
    float bu = takeO ? buO : buE;
    int   bx = takeO ? bxO : bxE;

    float max_iou = bi / bu;                 // single IEEE f32 division
    bool pos = (max_iou >= 0.5f);

    out_labels[i] = pos ? (float)gt_labels[bx] : 0.0f;

    float4 g = s_box[bx];                    // matched gt from LDS

    float pw = p.z - p.x;
    float ph = p.w - p.y;
    float px = p.x + 0.5f * pw;
    float py = p.y + 0.5f * ph;
    float gw = g.z - g.x;
    float gh = g.w - g.y;
    float gx = g.x + 0.5f * gw;
    float gy = g.y + 0.5f * gh;

    float tx = (gx - px) / pw;
    float ty = (gy - py) / ph;
    float tw = logf(gw / pw);
    float th = logf(gh / ph);

    float4 d;
    if (pos) { d.x = tx; d.y = ty; d.z = tw; d.w = th; }
    else     { d.x = 0.f; d.y = 0.f; d.z = 0.f; d.w = 0.f; }
    out_deltas[i] = d;
}

extern "C" void kernel_launch(void* const* d_in, const int* in_sizes, int n_in,
                              void* d_out, int out_size, void* d_ws, size_t ws_size,
                              hipStream_t stream) {
    const float4* proposals = (const float4*)d_in[0];
    const float4* gt_boxes  = (const float4*)d_in[1];
    const int*    gt_labels = (const int*)d_in[2];

    int N = in_sizes[0] / 4;   // 262144

    float*  out_labels = (float*)d_out;             // first N floats
    float4* out_deltas = (float4*)((float*)d_out + N);

    dim3 block(256);
    dim3 grid((N + 255) / 256);
    roi_assign_kernel<<<grid, block, 0, stream>>>(
        proposals, gt_boxes, gt_labels, out_labels, out_deltas, N);
}

// Round 4
// 94.510 us; speedup vs baseline: 1.2151x; 1.0346x over previous
//
#include <hip/hip_runtime.h>

#define M_GT 256

__global__ __launch_bounds__(256) void roi_assign_kernel(
    const float4* __restrict__ proposals,  // [N]
    const float4* __restrict__ gt_boxes,   // [256]
    const int*    __restrict__ gt_labels,  // [256]
    float*        __restrict__ out_labels, // [N]
    float4*       __restrict__ out_deltas, // [N]
    int N)
{
    __shared__ float4 s_box[M_GT];
    __shared__ float  s_area[M_GT];

    int tid = threadIdx.x;
    // stage all 256 GT boxes + areas (one per thread)
    float4 g0 = gt_boxes[tid];
    s_box[tid]  = g0;
    s_area[tid] = (g0.z - g0.x) * (g0.w - g0.y);
    __syncthreads();

    // lane pair (2k,2k+1) shares one proposal; parity picks the GT half
    int p_local = tid >> 1;
    int part    = tid & 1;
    int i = blockIdx.x * 128 + p_local;
    if (i >= N) return;   // uniform per pair (never taken at our sizes)

    float4 p = proposals[i];
    float areaA = (p.z - p.x) * (p.w - p.y);

    // argmax over t_j = inter_j / S_j  (S = areaA + areaB) — monotone in IoU.
    // two independent chains (even/odd j) for ILP on the select recurrence.
    int jbase = part << 7;                 // 0 or 128
    float biE = -1.f, bSE = 1.f; int bxE = jbase;
    float biO = -1.f, bSO = 1.f; int bxO = jbase + 1;

    const float2* s_area2 = reinterpret_cast<const float2*>(s_area);

#pragma unroll 8
    for (int k = 0; k < 64; ++k) {
        int j = jbase + (k << 1);
        float4 gE = s_box[j];
        float4 gO = s_box[j + 1];
        float2 ar = s_area2[j >> 1];       // areas for (j, j+1), one ds_read_b64

        {   // even chain
            float lx = fmaxf(p.x, gE.x), ly = fmaxf(p.y, gE.y);
            float rx = fminf(p.z, gE.z), ry = fminf(p.w, gE.w);
            float w = fmaxf(rx - lx, 0.f), h = fmaxf(ry - ly, 0.f);
            float inter = w * h;
            float S = areaA + ar.x;
            bool upd = (inter * bSE) > (biE * S);   // exact rational compare
            biE = upd ? inter : biE;
            bSE = upd ? S     : bSE;
            bxE = upd ? j     : bxE;
        }
        {   // odd chain
            float lx = fmaxf(p.x, gO.x), ly = fmaxf(p.y, gO.y);
            float rx = fminf(p.z, gO.z), ry = fminf(p.w, gO.w);
            float w = fmaxf(rx - lx, 0.f), h = fmaxf(ry - ly, 0.f);
            float inter = w * h;
            float S = areaA + ar.y;
            bool upd = (inter * bSO) > (biO * S);
            biO = upd ? inter : biO;
            bSO = upd ? S     : bSO;
            bxO = upd ? j + 1 : bxO;
        }
    }

    // merge even/odd chains; tie (equal cross-products) -> smaller index
    float ca = biO * bSE, cb = biE * bSO;
    bool takeO = (ca > cb) || ((ca == cb) && (bxO < bxE));
    float bi = takeO ? biO : biE;
    float bS = takeO ? bSO : bSE;
    int   bx = takeO ? bxO : bxE;

    // cross-lane merge between part0 (even lane) and part1 (odd lane).
    // adjacent-lane shfl_xor -> DPP, stays on the VALU pipe.
    float o_bi = __shfl_xor(bi, 1);
    float o_bS = __shfl_xor(bS, 1);
    int   o_bx = __shfl_xor(bx, 1);

    float b0i = part ? o_bi : bi,  b1i = part ? bi : o_bi;
    float b0S = part ? o_bS : bS,  b1S = part ? bS : o_bS;
    int   b0x = part ? o_bx : bx,  b1x = part ? bx : o_bx;

    // strict > : on tie keep part0 (all its indices are smaller)
    bool take1 = (b1i * b0S) > (b0i * b1S);
    float mI = take1 ? b1i : b0i;
    float mS = take1 ? b1S : b0S;
    int   mx = take1 ? b1x : b0x;

    float uni = mS - mI;                   // same rounding as ref's union
    float iou = mI / uni;                  // single IEEE f32 division
    bool pos = (iou >= 0.5f);

    if (part == 0) {
        // even lane: label
        out_labels[i] = pos ? (float)gt_labels[mx] : 0.0f;
    } else {
        // odd lane: box-delta encode
        float4 g = s_box[mx];
        float pw = p.z - p.x, ph = p.w - p.y;
        float px = p.x + 0.5f * pw, py = p.y + 0.5f * ph;
        float gw = g.z - g.x, gh = g.w - g.y;
        float gx = g.x + 0.5f * gw, gy = g.y + 0.5f * gh;
        float4 d;
        if (pos) {
            d.x = (gx - px) / pw;
            d.y = (gy - py) / ph;
            d.z = logf(gw / pw);
            d.w = logf(gh / ph);
        } else {
            d.x = 0.f; d.y = 0.f; d.z = 0.f; d.w = 0.f;
        }
        out_deltas[i] = d;
    }
}

extern "C" void kernel_launch(void* const* d_in, const int* in_sizes, int n_in,
                              void* d_out, int out_size, void* d_ws, size_t ws_size,
                              hipStream_t stream) {
    const float4* proposals = (const float4*)d_in[0];
    const float4* gt_boxes  = (const float4*)d_in[1];
    const int*    gt_labels = (const int*)d_in[2];

    int N = in_sizes[0] / 4;   // 262144

    float*  out_labels = (float*)d_out;               // first N floats
    float4* out_deltas = (float4*)((float*)d_out + N);

    dim3 block(256);
    dim3 grid((N + 127) / 128);   // 2 threads per proposal
    roi_assign_kernel<<<grid, block, 0, stream>>>(
        proposals, gt_boxes, gt_labels, out_labels, out_deltas, N);
}